// Round 1
// baseline (131.810 us; speedup 1.0000x reference)
//
#include <hip/hip_runtime.h>
#include <cstdint>

#define BB 4
#define NN 1024
#define DD 32
#define NWORDS 16           // NN / 64
#define RPB 16              // rows per block
#define NEG_INF_F (-1e10f)

typedef unsigned long long u64;

// Single fused kernel: 256 blocks x 256 threads, one block per 16 output rows.
// Each block:
//   A) packs edges[b, 0:64, :] into a 64x16 u64 bit-tile via __ballot (L2-hit reads)
//   B) packs neighbor word0 (cols 0..63) for its 16 rows via __ballot
//   C) computes the batch column-max of features (coalesced float4, L2-resident)
//   D) branchless OR-scan: row i saturated iff OR_{j in nb_i} tile[j][:] == all-ones
//   E) saturated rows (prob ~1) broadcast colmax; otherwise exact block-wide fallback.
__global__ __launch_bounds__(256, 1) void fused_kernel(
        const float* __restrict__ feat,
        const int*   __restrict__ edges,
        float*       __restrict__ out) {
    const int blk  = blockIdx.x;
    const int b    = blk >> 6;
    const int r0   = (blk & 63) * RPB;
    const int t    = threadIdx.x;
    const int lane = t & 63;
    const int wid  = t >> 6;

    __shared__ u64   s_tile[64 * NWORDS];        // 8 KB packed edges[b, 0:64, :]
    __shared__ u64   s_nb[RPB];                  // word0 per row
    __shared__ int   s_need[RPB];
    __shared__ __align__(16) float4 s_red[256];  // 4 KB colmax reduce
    // fallback-only:
    __shared__ int           s_ei[NN];
    __shared__ unsigned char s_reach[NN];
    __shared__ float s_m[256], s_u[256];

    if (t < RPB) s_need[t] = 0;

    const int* eb = edges + (size_t)b * NN * NN;

    // ---- Phase A: pack rows 0..63 via ballot. Wave wid owns rows wid*16..wid*16+15.
    // Per row: 16 coalesced dword loads (256 B each), 16 ballots -> 16 u64 words.
    {
        const int* rp = eb + (size_t)(wid * 16) * NN + lane;
#pragma unroll 2
        for (int jj = 0; jj < 16; ++jj) {
            const int j = wid * 16 + jj;
#pragma unroll
            for (int w = 0; w < NWORDS; ++w) {
                const int v = rp[(size_t)jj * NN + w * 64];
                const u64 bal = __ballot(v != 0);
                if (lane == 0) s_tile[j * NWORDS + w] = bal;
            }
        }
    }

    // ---- Phase B: neighbor word0 (cols 0..63) for my 16 rows (4 per wave) ----
#pragma unroll
    for (int q = 0; q < 4; ++q) {
        const int rr = wid * 4 + q;
        const int v  = eb[(size_t)(r0 + rr) * NN + lane];
        const u64 bal = __ballot(v != 0);
        if (lane == 0) s_nb[rr] = bal;
    }

    // ---- Phase C: colmax partials. Thread t -> chunk = t>>3 (32 row-chunks), d4 = t&7.
    // Load fb4[kk*256 + t]: each kk-iteration is a fully contiguous 4 KB block read.
    {
        const float4* fb4 = reinterpret_cast<const float4*>(feat + (size_t)b * NN * DD);
        float4 m = make_float4(-INFINITY, -INFINITY, -INFINITY, -INFINITY);
#pragma unroll 8
        for (int kk = 0; kk < 32; ++kk) {
            const float4 v = fb4[(size_t)kk * 256 + t];
            m.x = fmaxf(m.x, v.x); m.y = fmaxf(m.y, v.y);
            m.z = fmaxf(m.z, v.z); m.w = fmaxf(m.w, v.w);
        }
        s_red[t] = m;
    }
    __syncthreads();
    // reduce 32 chunks -> s_red[0..7] holds the per-batch column max (32 floats)
    for (int s = 16; s > 0; s >>= 1) {
        if (t < s * 8) {
            float4 a = s_red[t];
            const float4 c = s_red[t + s * 8];
            a.x = fmaxf(a.x, c.x); a.y = fmaxf(a.y, c.y);
            a.z = fmaxf(a.z, c.z); a.w = fmaxf(a.w, c.w);
            s_red[t] = a;
        }
        __syncthreads();
    }

    // ---- Phase D: branchless OR-scan saturation check ----
    const int il = t >> 4;
    const int w  = t & 15;
    {
        const u64 nb = s_nb[il];
        u64 acc = 0ull;
#pragma unroll
        for (int j = 0; j < 64; ++j) {
            const u64 msk = 0ull - ((nb >> j) & 1ull);
            acc |= s_tile[j * NWORDS + w] & msk;
        }
        if (acc != ~0ull) atomicAdd(&s_need[il], 1);
    }
    __syncthreads();

    // ---- Phase E: fast path — broadcast colmax ----
    float* orow_base = out + (size_t)(b * NN + r0) * DD;
    if (s_need[il] == 0) {
        reinterpret_cast<float2*>(orow_base + il * DD)[w] =
            reinterpret_cast<const float2*>(s_red)[w];
    }

    bool any = false;
#pragma unroll
    for (int r = 0; r < RPB; ++r) any = any || (s_need[r] != 0);
    if (!any) return;

    // ---- exact fallback (prob ~0): full-j reachability straight from edges ----
    for (int r = 0; r < RPB; ++r) {
        if (s_need[r] == 0) continue;           // block-uniform
        const int i = r0 + r;
        const int* ei = eb + (size_t)i * NN;
#pragma unroll
        for (int q = 0; q < 4; ++q) s_ei[t + q * 256] = ei[t + q * 256];
        __syncthreads();
#pragma unroll
        for (int kq = 0; kq < 4; ++kq) {
            const int k = t * 4 + kq;
            int reach = 0;
            for (int j = 0; j < NN; ++j) {
                if (s_ei[j] != 0 && eb[(size_t)j * NN + k] != 0) { reach = 1; break; }
            }
            s_reach[k] = (unsigned char)reach;
        }
        __syncthreads();
        const int d   = t & 31;
        const int kc8 = t >> 5;
        const float* fb = feat + (size_t)b * NN * DD;
        float mm = -INFINITY, um = -INFINITY;
        for (int kk = 0; kk < 128; ++kk) {
            const int k = kc8 * 128 + kk;
            const float f = fb[(size_t)k * DD + d];
            if (s_reach[k]) mm = fmaxf(mm, f); else um = fmaxf(um, f);
        }
        s_m[t] = mm; s_u[t] = um;
        __syncthreads();
        for (int s = 4; s > 0; s >>= 1) {
            if (kc8 < s) {
                s_m[kc8 * 32 + d] = fmaxf(s_m[kc8 * 32 + d], s_m[(kc8 + s) * 32 + d]);
                s_u[kc8 * 32 + d] = fmaxf(s_u[kc8 * 32 + d], s_u[(kc8 + s) * 32 + d]);
            }
            __syncthreads();
        }
        if (kc8 == 0)
            out[(size_t)(b * NN + i) * DD + d] = fmaxf(s_m[d], s_u[d] + NEG_INF_F);
        __syncthreads();
    }
}

extern "C" void kernel_launch(void* const* d_in, const int* in_sizes, int n_in,
                              void* d_out, int out_size, void* d_ws, size_t ws_size,
                              hipStream_t stream) {
    const float* feat  = (const float*)d_in[0];   // [B,N,D] f32
    const int*   edges = (const int*)d_in[1];     // [B,N,N] i32
    float*       out   = (float*)d_out;           // [B,N,D] f32
    (void)d_ws; (void)ws_size;

    fused_kernel<<<BB * 64, 256, 0, stream>>>(feat, edges, out);
}

// Round 2
// 70.872 us; speedup vs baseline: 1.8598x; 1.8598x over previous
//
#include <hip/hip_runtime.h>
#include <cstdint>

#define BB 4
#define NN 1024
#define DD 32
#define NWORDS 16           // NN / 64
#define RPB 16              // output rows per block
#define BLOCK 512
#define NEG_INF_F (-1e10f)

typedef unsigned long long u64;

// Single fused kernel: 256 blocks x 512 threads, one block per 16 output rows.
//   A) pack edges[b, 0:64, :] into 64x16 u64 bit-tile: independent int4 loads
//      into registers first, then 4-lane shfl_xor OR-combine (no ballot-on-load,
//      no LDS atomics -> nothing serializes on vmcnt)
//   B) pack neighbor word0 (cols 0..63) for the block's 16 rows (1 int4/thread)
//   C) batch column-max of features (coalesced float4, fully independent loads)
//   D) branchless OR-scan: row i saturated iff OR_{j in nb_i, j<64} tile[j] == ~0
//   E) saturated rows (prob ~1) broadcast colmax; else exact block-wide fallback.
__global__ __launch_bounds__(BLOCK, 1) void fused_kernel(
        const float* __restrict__ feat,
        const int*   __restrict__ edges,
        float*       __restrict__ out) {
    const int blk  = blockIdx.x;
    const int b    = blk >> 6;
    const int r0   = (blk & 63) * RPB;
    const int t    = threadIdx.x;

    __shared__ u64   s_tile[64 * NWORDS];        // 8 KB packed edges[b, 0:64, :]
    __shared__ u64   s_nb[RPB];                  // word0 per output row
    __shared__ int   s_need[RPB];
    __shared__ __align__(16) float4 s_red[BLOCK];// 8 KB colmax reduce
    // fallback-only:
    __shared__ int           s_ei[NN];
    __shared__ unsigned char s_reach[NN];
    __shared__ float s_m[BLOCK], s_u[BLOCK];

    if (t < RPB) s_need[t] = 0;

    const int*  eb = edges + (size_t)b * NN * NN;
    const int4* e4 = reinterpret_cast<const int4*>(eb);

    // ---- Phase A: pack tile rows 0..63 ----
    // Wave wid (= t>>6) owns row j = p*8 + wid each pass. Lane c = t&63 covers
    // columns 16c..16c+15 via 4 independent int4 loads -> 16-bit chunk ->
    // OR across 4 consecutive lanes -> u64 word, one ds_write per 4 lanes.
    {
        const int c  = t & 63;
        const int jr = t >> 6;
#pragma unroll
        for (int p = 0; p < 8; ++p) {
            const int j = p * 8 + jr;
            int4 v[4];
#pragma unroll
            for (int q = 0; q < 4; ++q)
                v[q] = e4[(size_t)j * 256 + c * 4 + q];
            unsigned ch = 0;
#pragma unroll
            for (int q = 0; q < 4; ++q) {
                ch |= (v[q].x != 0 ? 1u : 0u) << (q * 4 + 0);
                ch |= (v[q].y != 0 ? 1u : 0u) << (q * 4 + 1);
                ch |= (v[q].z != 0 ? 1u : 0u) << (q * 4 + 2);
                ch |= (v[q].w != 0 ? 1u : 0u) << (q * 4 + 3);
            }
            u64 my = (u64)ch << ((c & 3) * 16);
            my |= __shfl_xor(my, 1, 64);
            my |= __shfl_xor(my, 2, 64);
            if ((c & 3) == 0) s_tile[j * NWORDS + (c >> 2)] = my;
        }
    }

    // ---- Phase B: word0 (cols 0..63) for my 16 rows. Waves 0..3 only (full waves).
    if (t < 256) {
        const int rr = t >> 4;
        const int cc = t & 15;
        const int4 v = e4[(size_t)(r0 + rr) * 256 + cc];
        const unsigned nib = (v.x != 0 ? 1u : 0u) | (v.y != 0 ? 2u : 0u)
                           | (v.z != 0 ? 4u : 0u) | (v.w != 0 ? 8u : 0u);
        u64 my = (u64)nib << (cc * 4);
        my |= __shfl_xor(my, 1, 64);
        my |= __shfl_xor(my, 2, 64);
        my |= __shfl_xor(my, 4, 64);
        my |= __shfl_xor(my, 8, 64);
        if (cc == 0) s_nb[rr] = my;
    }

    // ---- Phase C: colmax partials. 16 fully-contiguous 8 KB sweeps. ----
    {
        const float4* fb4 = reinterpret_cast<const float4*>(feat + (size_t)b * NN * DD);
        float4 m = make_float4(-INFINITY, -INFINITY, -INFINITY, -INFINITY);
#pragma unroll 8
        for (int kk = 0; kk < 16; ++kk) {
            const float4 v = fb4[(size_t)kk * BLOCK + t];
            m.x = fmaxf(m.x, v.x); m.y = fmaxf(m.y, v.y);
            m.z = fmaxf(m.z, v.z); m.w = fmaxf(m.w, v.w);
        }
        s_red[t] = m;
    }
    __syncthreads();

    // ---- Phase D: branchless OR-scan (threads 0..255; one (row, word) each) ----
    const int il = t >> 4;          // valid for t<256
    const int w  = t & 15;
    if (t < 256) {
        const u64 nb = s_nb[il];
        u64 acc = 0ull;
#pragma unroll
        for (int j = 0; j < 64; ++j) {
            const u64 msk = 0ull - ((nb >> j) & 1ull);
            acc |= s_tile[j * NWORDS + w] & msk;
        }
        if (acc != ~0ull) atomicAdd(&s_need[il], 1);
    }

    // reduce 64 chunks -> s_red[0..7] = per-batch column max (32 floats)
    for (int s = 32; s > 0; s >>= 1) {
        if (t < s * 8) {
            float4 a = s_red[t];
            const float4 c = s_red[t + s * 8];
            a.x = fmaxf(a.x, c.x); a.y = fmaxf(a.y, c.y);
            a.z = fmaxf(a.z, c.z); a.w = fmaxf(a.w, c.w);
            s_red[t] = a;
        }
        __syncthreads();
    }

    // ---- Phase E: fast path — broadcast colmax ----
    float* orow_base = out + (size_t)(b * NN + r0) * DD;
    if (t < 256 && s_need[il] == 0) {
        reinterpret_cast<float2*>(orow_base + il * DD)[w] =
            reinterpret_cast<const float2*>(s_red)[w];
    }

    bool any = false;
#pragma unroll
    for (int r = 0; r < RPB; ++r) any = any || (s_need[r] != 0);
    if (!any) return;

    // ---- exact fallback (prob ~0): full-j reachability straight from edges ----
    const float* fb = feat + (size_t)b * NN * DD;
    for (int r = 0; r < RPB; ++r) {
        if (s_need[r] == 0) continue;           // block-uniform
        const int i = r0 + r;
        const int* ei = eb + (size_t)i * NN;
        s_ei[t]       = ei[t];
        s_ei[t + 512] = ei[t + 512];
        __syncthreads();
#pragma unroll
        for (int kq = 0; kq < 2; ++kq) {
            const int k = t * 2 + kq;
            int reach = 0;
            for (int j = 0; j < NN; ++j) {
                if (s_ei[j] != 0 && eb[(size_t)j * NN + k] != 0) { reach = 1; break; }
            }
            s_reach[k] = (unsigned char)reach;
        }
        __syncthreads();
        const int d  = t & 31;
        const int kc = t >> 5;                  // 16 chunks of 64 feature rows
        float mm = -INFINITY, um = -INFINITY;
        for (int kk = 0; kk < 64; ++kk) {
            const int k = kc * 64 + kk;
            const float f = fb[(size_t)k * DD + d];
            if (s_reach[k]) mm = fmaxf(mm, f); else um = fmaxf(um, f);
        }
        s_m[t] = mm; s_u[t] = um;
        __syncthreads();
        for (int s = 8; s > 0; s >>= 1) {
            if (kc < s) {
                s_m[kc * 32 + d] = fmaxf(s_m[kc * 32 + d], s_m[(kc + s) * 32 + d]);
                s_u[kc * 32 + d] = fmaxf(s_u[kc * 32 + d], s_u[(kc + s) * 32 + d]);
            }
            __syncthreads();
        }
        if (kc == 0)
            out[(size_t)(b * NN + i) * DD + d] = fmaxf(s_m[d], s_u[d] + NEG_INF_F);
        __syncthreads();
    }
}

extern "C" void kernel_launch(void* const* d_in, const int* in_sizes, int n_in,
                              void* d_out, int out_size, void* d_ws, size_t ws_size,
                              hipStream_t stream) {
    const float* feat  = (const float*)d_in[0];   // [B,N,D] f32
    const int*   edges = (const int*)d_in[1];     // [B,N,N] i32
    float*       out   = (float*)d_out;           // [B,N,D] f32
    (void)d_ws; (void)ws_size;

    fused_kernel<<<BB * 64, BLOCK, 0, stream>>>(feat, edges, out);
}